// Round 1
// baseline (67.752 us; speedup 1.0000x reference)
//
#include <hip/hip_runtime.h>

// Problem geometry (fixed by the reference):
//   x : (2, 8, 512, 512) f32, gm : (2, 1, 512, 512) f32
//   out = concat( bg:(2,8,512,512,16), on:(2,1,512,512,16) ) f32
// Key insight: hg==i, wg==j exactly -> splat is 1-D along r only; every
// output voxel is written by exactly one pixel. Pure streaming-write kernel.

#define HW      (512 * 512)           // 262144 = 2^18
#define NPIX    (2 * HW)              // 524288 pixels total
#define BG_SIZE (2 * 8 * HW * 16)     // 67108864 floats

__global__ __launch_bounds__(256) void splat_r_kernel(
    const float* __restrict__ x,
    const float* __restrict__ gm,
    float* __restrict__ out)
{
    // 4 threads per pixel; thread owns r-chunk q (4 floats, 16B).
    int g     = blockIdx.x * 256 + threadIdx.x;
    int pixel = g >> 2;          // (n*HW + i*512 + j)
    int q     = g & 3;

    int n   = pixel >> 18;       // HW = 2^18
    int rem = pixel & (HW - 1);  // i*512 + j

    // r-splat weights
    float pr  = gm[pixel] * 15.0f;
    float r0f = floorf(pr);
    float t   = pr - r0f;
    int   r0  = (int)r0f;
    int   i0  = min(max(r0,     0), 15);
    int   i1  = min(max(r0 + 1, 0), 15);
    float w0  = 1.0f - t;

    int rbase = q * 4;
    // statically-built weight vector for this thread's 4 r-slots
    float wk0 = ((rbase + 0) == i0 ? w0 : 0.0f) + ((rbase + 0) == i1 ? t : 0.0f);
    float wk1 = ((rbase + 1) == i0 ? w0 : 0.0f) + ((rbase + 1) == i1 ? t : 0.0f);
    float wk2 = ((rbase + 2) == i0 ? w0 : 0.0f) + ((rbase + 2) == i1 ? t : 0.0f);
    float wk3 = ((rbase + 3) == i0 ? w0 : 0.0f) + ((rbase + 3) == i1 ? t : 0.0f);
    float4 w  = make_float4(wk0, wk1, wk2, wk3);

    // bg channels: out[(((n*8+c)*HW + rem)*16) + rbase .. +3]
    const float* xp = x + (n * 8) * HW + rem;
    #pragma unroll
    for (int c = 0; c < 8; ++c) {
        float v = xp[c * HW];
        float4 o = make_float4(v * w.x, v * w.y, v * w.z, v * w.w);
        *(float4*)(out + (((n * 8 + c) * HW + rem) * 16 + rbase)) = o;
    }

    // ones channel -> on[(pixel*16) + rbase .. +3] after bg block
    *(float4*)(out + BG_SIZE + (pixel * 16 + rbase)) = w;
}

extern "C" void kernel_launch(void* const* d_in, const int* in_sizes, int n_in,
                              void* d_out, int out_size, void* d_ws, size_t ws_size,
                              hipStream_t stream) {
    const float* x  = (const float*)d_in[0];
    const float* gm = (const float*)d_in[1];
    float* out = (float*)d_out;

    const int total_threads = NPIX * 4;            // 2,097,152
    const int block = 256;
    const int grid  = total_threads / block;       // 8192
    splat_r_kernel<<<grid, block, 0, stream>>>(x, gm, out);
}